// Round 10
// baseline (803.628 us; speedup 1.0000x reference)
//
#include <hip/hip_runtime.h>
#include <math.h>

// T=1000, B=256, F_IN=13 x3 -> 39 features, H=100, gates r,z,n (3H=300), 20 classes
#define T_STEPS 1000
#define BATCH   256
#define FIN     13
#define XDIM    39
#define HDIM    100
#define NCLS    20

#define NCONS   448     // 7 consumer waves: quad per hidden unit, 4 col-parts/lane
#define NTHR    640     // + 3 producer waves (192 threads, 150 active)
#define HPAD    112     // h padded to 4*28 for uniform float4 reads
#define PCOLS   28      // columns per lane part

typedef float v2f __attribute__((ext_vector_type(2)));

// v_pk_fma_f32: 2 independent f32 MACs per instruction (VOP3P; CDNA1+, heavily
// used in AITER gfx950 asm). No builtin -> inline asm. NON-volatile + pure
// dataflow so LLVM can schedule/interleave freely.
#define PKFMA(acc, a, b) asm("v_pk_fma_f32 %0, %1, %2, %0" : "+v"(acc) : "v"(a), "v"(b))
#define PKADD(d, a, b)   asm("v_pk_add_f32 %0, %1, %2"     : "=v"(d)   : "v"(a), "v"(b))

__device__ __forceinline__ float fast_sigmoid(float v) {
    return 1.f / (1.f + __expf(-v));
}
// quad_perm butterflies (VALU DPP; all 4 quad lanes active in consumer waves)
__device__ __forceinline__ float quad_xor1(float v) {
    return __int_as_float(__builtin_amdgcn_update_dpp(0, __float_as_int(v), 0xB1, 0xF, 0xF, true)); // [1,0,3,2]
}
__device__ __forceinline__ float quad_xor2(float v) {
    return __int_as_float(__builtin_amdgcn_update_dpp(0, __float_as_int(v), 0x4E, 0xF, 0xF, true)); // [2,3,0,1]
}

// R9 reading: useful FLOPs = 19% of FP32 pipe but VALUBusy 84% -> issue stream
// ~4x the useful math (moves/shuttles + plain FMA count). Lever: halve the
// instruction count with v_pk_fma_f32 (84->42 consumer, 80->40 producer MAC
// instrs). Also: flat gib + ds_write_b64 kills the 1.49e7 producer write
// conflicts (R5 measured 0 with this layout); consumers read 3 bcast b32s.
__attribute__((amdgpu_flat_work_group_size(NTHR, NTHR), amdgpu_waves_per_eu(2, 3)))
__global__ void gru_persistent(const float* __restrict__ mfcc0,
                               const float* __restrict__ mfcc1,
                               const float* __restrict__ mfcc2,
                               const float* __restrict__ len0,
                               const float* __restrict__ W_ih,
                               const float* __restrict__ W_hh,
                               const float* __restrict__ b_ih,
                               const float* __restrict__ b_hh,
                               const float* __restrict__ W_out,
                               const float* __restrict__ b_out,
                               float* __restrict__ out)
{
    const int b   = blockIdx.x;
    const int tid = threadIdx.x;

    __shared__ __align__(16) float Vh[2][HPAD];       // h(t), pads [100..112) stay 0
    __shared__ __align__(16) float gib[2][304];       // gi FLAT: [g*100 + j] (+4 pad)
    __shared__ __align__(16) float xbuf[2][40];       // x staging (39 + zero pad)
    __shared__ float feat[2 * HDIM];

    const bool isCons = (tid < NCONS);

    // ---- consumer geometry: quad q = hidden unit j, lane part p ----
    const int q  = tid >> 2;                    // 0..111 (consumers), idle q>=100
    const int p  = tid & 3;                     // column part
    const int j  = (q < HDIM) ? q : (HDIM - 1); // clamped unit id

    // ---- producer geometry: rows (gA, gA+1) of the 300 gi rows ----
    const int q0 = isCons ? 0 : (tid - NCONS);  // 0..191, active <150
    const int gA = 2 * ((q0 < 150) ? q0 : 149);
    const int gB = gA + 1;

    // ---- SHARED weight registers as packed pairs ----
    // consumers: w2[0..41] = 3 gates x 14 pairs; producers: w2[0..19]=rowA, [20..39]=rowB
    v2f w2[42];
    float bh0 = 0.f, bh1 = 0.f, bh2 = 0.f;      // consumer: b_hh triple; producer: b_ih pair
    if (isCons) {
        const int base = PCOLS * p;
        #pragma unroll
        for (int rr = 0; rr < 3; ++rr) {
            const float* src = W_hh + (rr * HDIM + j) * HDIM;
            #pragma unroll
            for (int i = 0; i < 7; ++i) {
                const int c = base + 4 * i;
                v2f t0, t1;
                t0.x = (c + 0 < HDIM) ? src[c + 0] : 0.f;
                t0.y = (c + 1 < HDIM) ? src[c + 1] : 0.f;
                t1.x = (c + 2 < HDIM) ? src[c + 2] : 0.f;
                t1.y = (c + 3 < HDIM) ? src[c + 3] : 0.f;
                w2[rr * 14 + 2 * i]     = t0;
                w2[rr * 14 + 2 * i + 1] = t1;
            }
        }
        bh0 = b_hh[j]; bh1 = b_hh[HDIM + j]; bh2 = b_hh[2 * HDIM + j];
    } else {
        const float* sA = W_ih + gA * XDIM;
        const float* sB = W_ih + gB * XDIM;
        #pragma unroll
        for (int i = 0; i < 9; ++i) {
            v2f a0; a0.x = sA[4*i];   a0.y = sA[4*i+1];
            v2f a1; a1.x = sA[4*i+2]; a1.y = sA[4*i+3];
            v2f b0; b0.x = sB[4*i];   b0.y = sB[4*i+1];
            v2f b1; b1.x = sB[4*i+2]; b1.y = sB[4*i+3];
            w2[2*i] = a0; w2[2*i+1] = a1; w2[20+2*i] = b0; w2[20+2*i+1] = b1;
        }
        { v2f t; t.x = sA[36]; t.y = sA[37]; w2[18] = t; }
        { v2f t; t.x = sA[38]; t.y = 0.f;    w2[19] = t; }   // pairs with xbuf[39]=0
        { v2f t; t.x = sB[36]; t.y = sB[37]; w2[38] = t; }
        { v2f t; t.x = sB[38]; t.y = 0.f;    w2[39] = t; }
        { v2f z; z.x = 0.f; z.y = 0.f; w2[40] = z; w2[41] = z; }
        bh0 = b_ih[gA]; bh1 = b_ih[gB];
    }

    // ---- producer x streaming source ----
    const float* xsrc = mfcc0;
    int xoff = b * FIN;
    if (!isCons && q0 < XDIM) {
        const int f = q0 % FIN;
        xsrc = (q0 < FIN) ? mfcc0 : (q0 < 2 * FIN ? mfcc1 : mfcc2);
        xoff = b * FIN + f;
    }

    // ---- prologue: h0 = 0 (both buffers, pads included), stage x(0)/x(1), gi(0) ----
    if (tid < HPAD) { Vh[0][tid] = 0.f; Vh[1][tid] = 0.f; }
    if (tid < 40) {
        float v0 = 0.f, v1 = 0.f;
        if (tid < XDIM) {
            const int f = tid % FIN;
            const float* xs = (tid < FIN) ? mfcc0 : (tid < 2 * FIN ? mfcc1 : mfcc2);
            v0 = xs[b * FIN + f];
            v1 = xs[(size_t)BATCH * FIN + b * FIN + f];
        }
        xbuf[0][tid] = v0; xbuf[1][tid] = v1;
    }
    __syncthreads();
    if (!isCons && q0 < 150) {
        const float4* X4 = (const float4*)xbuf[0];
        v2f A0 = {0,0}, A1 = {0,0}, B0 = {0,0}, B1 = {0,0};
        #pragma unroll
        for (int i = 0; i < 10; ++i) {
            const float4 vv = X4[i];
            v2f vlo; vlo.x = vv.x; vlo.y = vv.y;
            v2f vhi; vhi.x = vv.z; vhi.y = vv.w;
            PKFMA(A0, w2[2*i],      vlo); PKFMA(A1, w2[2*i+1],    vhi);
            PKFMA(B0, w2[20+2*i],   vlo); PKFMA(B1, w2[20+2*i+1], vhi);
        }
        v2f As, Bs; PKADD(As, A0, A1); PKADD(Bs, B0, B1);
        v2f gv; gv.x = bh0 + (As.x + As.y); gv.y = bh1 + (Bs.x + Bs.y);
        *(v2f*)&gib[0][gA] = gv;                     // ds_write_b64, linear
    }
    __syncthreads();

    float hreg = 0.f;                 // h_j, kept in registers (all 4 quad lanes)
    float sum = 0.f, mx = -INFINITY;

    for (int t = 0; t < T_STEPS; ++t) {
        const int cur = t & 1;
        const int nxt = cur ^ 1;

        if (isCons) {
            // ---- gi reads issued FIRST (3 bcast b32, 16 banks/wave, conflict-free) ----
            const float gr = gib[cur][j];
            const float gz = gib[cur][HDIM + j];
            const float gn = gib[cur][2 * HDIM + j];
            // ---- GEMV: 7 bcast float4 reads, 3 gates x 28 cols, packed MACs ----
            const float4* V4 = (const float4*)(Vh[cur] + p * PCOLS);
            v2f A0={0,0},A1={0,0},B0={0,0},B1={0,0},C0={0,0},C1={0,0};
            #pragma unroll
            for (int i = 0; i < 7; ++i) {
                const float4 vv = V4[i];
                v2f vlo; vlo.x = vv.x; vlo.y = vv.y;
                v2f vhi; vhi.x = vv.z; vhi.y = vv.w;
                PKFMA(A0, w2[2*i],      vlo); PKFMA(A1, w2[2*i+1],    vhi);
                PKFMA(B0, w2[14+2*i],   vlo); PKFMA(B1, w2[14+2*i+1], vhi);
                PKFMA(C0, w2[28+2*i],   vlo); PKFMA(C1, w2[28+2*i+1], vhi);
            }
            v2f As, Bs, Cs;
            PKADD(As, A0, A1); PKADD(Bs, B0, B1); PKADD(Cs, C0, C1);
            float s0 = As.x + As.y;
            float s1 = Bs.x + Bs.y;
            float s2 = Cs.x + Cs.y;
            // ---- quad butterfly (DPP): all 4 lanes get full sums ----
            s0 += quad_xor1(s0); s1 += quad_xor1(s1); s2 += quad_xor1(s2);
            s0 += quad_xor2(s0); s1 += quad_xor2(s1); s2 += quad_xor2(s2);
            // ---- gates + state update, fully in-register ----
            const float rg = fast_sigmoid(gr + s0 + bh0);
            const float zg = fast_sigmoid(gz + s1 + bh1);
            const float na = fmaf(rg, s2 + bh2, gn);
            const float ng = fmaf(2.f, fast_sigmoid(2.f * na), -1.f); // tanh
            const float hv = fmaf(zg, hreg - ng, ng);              // (1-z)*n + z*h
            hreg = hv;
            sum += hv; mx = fmaxf(mx, hv);
            if (p == 0 && q < HDIM) Vh[nxt][q] = hv;               // publish h(t+1)
        } else {
            // ---- producers: prefetch x(t+2), compute gi(t+1) into gib[nxt] ----
            float xv = 0.f;
            const bool doX = (q0 < XDIM) && (t + 2 < T_STEPS);
            if (doX) xv = xsrc[(size_t)(t + 2) * (BATCH * FIN) + xoff];
            if ((t + 1 < T_STEPS) && q0 < 150) {
                const float4* X4 = (const float4*)xbuf[nxt];
                v2f A0 = {0,0}, A1 = {0,0}, B0 = {0,0}, B1 = {0,0};
                #pragma unroll
                for (int i = 0; i < 10; ++i) {
                    const float4 vv = X4[i];
                    v2f vlo; vlo.x = vv.x; vlo.y = vv.y;
                    v2f vhi; vhi.x = vv.z; vhi.y = vv.w;
                    PKFMA(A0, w2[2*i],      vlo); PKFMA(A1, w2[2*i+1],    vhi);
                    PKFMA(B0, w2[20+2*i],   vlo); PKFMA(B1, w2[20+2*i+1], vhi);
                }
                v2f As, Bs; PKADD(As, A0, A1); PKADD(Bs, B0, B1);
                v2f gv; gv.x = bh0 + (As.x + As.y); gv.y = bh1 + (Bs.x + Bs.y);
                *(v2f*)&gib[nxt][gA] = gv;           // ds_write_b64, linear
            }
            if (doX) xbuf[cur][q0] = xv;
        }
        __syncthreads();
    }

    // ---- pooling + output linear ----
    if (isCons && p == 0 && q < HDIM) {
        feat[q]        = sum / len0[b];
        feat[HDIM + q] = mx;
    }
    __syncthreads();

    if (tid < NCLS) {
        float acc = b_out[tid];
        #pragma unroll 4
        for (int k = 0; k < 2 * HDIM; ++k)
            acc = fmaf(W_out[tid * 2 * HDIM + k], feat[k], acc);
        out[b * NCLS + tid] = acc;
    }
}

extern "C" void kernel_launch(void* const* d_in, const int* in_sizes, int n_in,
                              void* d_out, int out_size, void* d_ws, size_t ws_size,
                              hipStream_t stream)
{
    const float* mfcc0 = (const float*)d_in[0];
    const float* mfcc1 = (const float*)d_in[1];
    const float* mfcc2 = (const float*)d_in[2];
    const float* len0  = (const float*)d_in[3];
    const float* W_ih  = (const float*)d_in[4];
    const float* W_hh  = (const float*)d_in[5];
    const float* b_ih  = (const float*)d_in[6];
    const float* b_hh  = (const float*)d_in[7];
    const float* W_out = (const float*)d_in[8];
    const float* b_out = (const float*)d_in[9];
    float* out = (float*)d_out;

    gru_persistent<<<BATCH, NTHR, 0, stream>>>(
        mfcc0, mfcc1, mfcc2, len0, W_ih, W_hh, b_ih, b_hh, W_out, b_out, out);
}

// Round 11
// 797.981 us; speedup vs baseline: 1.0071x; 1.0071x over previous
//
#include <hip/hip_runtime.h>
#include <math.h>

// T=1000, B=256, F_IN=13 x3 -> 39 features, H=100, gates r,z,n (3H=300), 20 classes
#define T_STEPS 1000
#define BATCH   256
#define FIN     13
#define XDIM    39
#define HDIM    100
#define NCLS    20

#define NCONS   448     // 7 consumer waves: quad per hidden unit, 4 col-parts/lane
#define NTHR    640     // + 3 producer waves (192 threads, 150 active)
#define HPAD    112     // h padded to 4*28 for uniform float4 reads
#define PCOLS   28      // columns per lane part

typedef float v2f __attribute__((ext_vector_type(2)));

// Packed FP32 MAC via compiler-native llvm.fma.v2f32 -> v_pk_fma_f32 (gfx90a+).
// R10 lesson: inline-asm "v" constraints forbid AGPR operands, forcing
// v_accvgpr_read shuttles of the AGPR-resident weight set (VGPR_Count=64,
// no scratch) -> chain serialization, +10% time. Native builtins keep AGPRs
// directly readable by the VALU (unified file) -> no shuttles.
__device__ __forceinline__ v2f pk_fma(v2f a, v2f b, v2f c) {
    return __builtin_elementwise_fma(a, b, c);
}

__device__ __forceinline__ float fast_sigmoid(float v) {
    return 1.f / (1.f + __expf(-v));
}
// quad_perm butterflies (VALU DPP; all 4 quad lanes active in consumer waves)
__device__ __forceinline__ float quad_xor1(float v) {
    return __int_as_float(__builtin_amdgcn_update_dpp(0, __float_as_int(v), 0xB1, 0xF, 0xF, true)); // [1,0,3,2]
}
__device__ __forceinline__ float quad_xor2(float v) {
    return __int_as_float(__builtin_amdgcn_update_dpp(0, __float_as_int(v), 0x4E, 0xF, 0xF, true)); // [2,3,0,1]
}

// R9 (735us, proven) + two validated changes:
//  1. flat gib[g*100+j] + ds_write_b64 producer writes: bank conflicts
//     1.485e7 -> 0 (validated R5 and R10).
//  2. packed f32 math via __builtin_elementwise_fma on float2 views of the
//     R9 float4 weight layout: consumer 84->42, producer 80->40 MAC instrs.
//     Weight STORAGE unchanged from R9 (float4 w[21], allocator-proven).
__attribute__((amdgpu_flat_work_group_size(NTHR, NTHR), amdgpu_waves_per_eu(2, 3)))
__global__ void gru_persistent(const float* __restrict__ mfcc0,
                               const float* __restrict__ mfcc1,
                               const float* __restrict__ mfcc2,
                               const float* __restrict__ len0,
                               const float* __restrict__ W_ih,
                               const float* __restrict__ W_hh,
                               const float* __restrict__ b_ih,
                               const float* __restrict__ b_hh,
                               const float* __restrict__ W_out,
                               const float* __restrict__ b_out,
                               float* __restrict__ out)
{
    const int b   = blockIdx.x;
    const int tid = threadIdx.x;

    __shared__ __align__(16) float Vh[2][HPAD];       // h(t), pads [100..112) stay 0
    __shared__ __align__(16) float gib[2][304];       // gi FLAT: [g*100 + j] (+4 pad)
    __shared__ __align__(16) float xbuf[2][40];       // x staging (39 + zero pad)
    __shared__ float feat[2 * HDIM];

    const bool isCons = (tid < NCONS);

    // ---- consumer geometry: quad q = hidden unit j, lane part p ----
    const int q  = tid >> 2;                    // 0..111 (consumers), idle q>=100
    const int p  = tid & 3;                     // column part
    const int j  = (q < HDIM) ? q : (HDIM - 1); // clamped unit id

    // ---- producer geometry: rows (gA, gA+1) of the 300 gi rows ----
    const int q0 = isCons ? 0 : (tid - NCONS);  // 0..191, active <150
    const int gA = 2 * ((q0 < 150) ? q0 : 149);
    const int gB = gA + 1;

    // ---- SHARED weight registers (R9 layout): consumers w[0..20], producers w[0..19] ----
    float4 w[21];
    float  bh0 = 0.f, bh1 = 0.f, bh2 = 0.f;     // consumer: b_hh triple; producer: b_ih pair
    if (isCons) {
        const int base = PCOLS * p;
        #pragma unroll
        for (int rr = 0; rr < 3; ++rr) {
            const float* src = W_hh + (rr * HDIM + j) * HDIM;
            #pragma unroll
            for (int i = 0; i < 7; ++i) {
                const int c = base + 4 * i;
                float4 t;
                t.x = (c + 0 < HDIM) ? src[c + 0] : 0.f;
                t.y = (c + 1 < HDIM) ? src[c + 1] : 0.f;
                t.z = (c + 2 < HDIM) ? src[c + 2] : 0.f;
                t.w = (c + 3 < HDIM) ? src[c + 3] : 0.f;
                w[rr * 7 + i] = t;
            }
        }
        bh0 = b_hh[j]; bh1 = b_hh[HDIM + j]; bh2 = b_hh[2 * HDIM + j];
    } else {
        const float* sA = W_ih + gA * XDIM;
        const float* sB = W_ih + gB * XDIM;
        #pragma unroll
        for (int i = 0; i < 9; ++i) {
            w[i]      = make_float4(sA[4*i], sA[4*i+1], sA[4*i+2], sA[4*i+3]);
            w[10 + i] = make_float4(sB[4*i], sB[4*i+1], sB[4*i+2], sB[4*i+3]);
        }
        w[9]  = make_float4(sA[36], sA[37], sA[38], 0.f);   // pairs with xbuf[39]=0
        w[19] = make_float4(sB[36], sB[37], sB[38], 0.f);
        w[20] = make_float4(0, 0, 0, 0);
        bh0 = b_ih[gA]; bh1 = b_ih[gB];
    }

    // ---- producer x streaming source ----
    const float* xsrc = mfcc0;
    int xoff = b * FIN;
    if (!isCons && q0 < XDIM) {
        const int f = q0 % FIN;
        xsrc = (q0 < FIN) ? mfcc0 : (q0 < 2 * FIN ? mfcc1 : mfcc2);
        xoff = b * FIN + f;
    }

    // ---- prologue: h0 = 0 (both buffers, pads included), stage x(0)/x(1), gi(0) ----
    if (tid < HPAD) { Vh[0][tid] = 0.f; Vh[1][tid] = 0.f; }
    if (tid < 40) {
        float v0 = 0.f, v1 = 0.f;
        if (tid < XDIM) {
            const int f = tid % FIN;
            const float* xs = (tid < FIN) ? mfcc0 : (tid < 2 * FIN ? mfcc1 : mfcc2);
            v0 = xs[b * FIN + f];
            v1 = xs[(size_t)BATCH * FIN + b * FIN + f];
        }
        xbuf[0][tid] = v0; xbuf[1][tid] = v1;
    }
    __syncthreads();
    if (!isCons && q0 < 150) {
        const float4* X4 = (const float4*)xbuf[0];
        v2f A0 = {0,0}, A1 = {0,0}, B0 = {0,0}, B1 = {0,0};
        #pragma unroll
        for (int i = 0; i < 10; ++i) {
            const float4 vv = X4[i];
            const v2f vlo = {vv.x, vv.y}, vhi = {vv.z, vv.w};
            A0 = pk_fma((v2f){w[i].x,    w[i].y},    vlo, A0);
            A1 = pk_fma((v2f){w[i].z,    w[i].w},    vhi, A1);
            B0 = pk_fma((v2f){w[10+i].x, w[10+i].y}, vlo, B0);
            B1 = pk_fma((v2f){w[10+i].z, w[10+i].w}, vhi, B1);
        }
        const v2f As = A0 + A1, Bs = B0 + B1;
        v2f gv; gv.x = bh0 + (As.x + As.y); gv.y = bh1 + (Bs.x + Bs.y);
        *(v2f*)&gib[0][gA] = gv;                     // ds_write_b64, linear
    }
    __syncthreads();

    float hreg = 0.f;                 // h_j, kept in registers (all 4 quad lanes)
    float sum = 0.f, mx = -INFINITY;

    for (int t = 0; t < T_STEPS; ++t) {
        const int cur = t & 1;
        const int nxt = cur ^ 1;

        if (isCons) {
            // ---- gi reads issued FIRST (3 bcast b32, conflict-free) ----
            const float gr = gib[cur][j];
            const float gz = gib[cur][HDIM + j];
            const float gn = gib[cur][2 * HDIM + j];
            // ---- GEMV: 7 bcast float4 reads, 3 gates x 28 cols, packed MACs ----
            const float4* V4 = (const float4*)(Vh[cur] + p * PCOLS);
            v2f A0={0,0},A1={0,0},B0={0,0},B1={0,0},C0={0,0},C1={0,0};
            #pragma unroll
            for (int i = 0; i < 7; ++i) {
                const float4 vv = V4[i];
                const v2f vlo = {vv.x, vv.y}, vhi = {vv.z, vv.w};
                A0 = pk_fma((v2f){w[i].x,     w[i].y},     vlo, A0);
                A1 = pk_fma((v2f){w[i].z,     w[i].w},     vhi, A1);
                B0 = pk_fma((v2f){w[7+i].x,   w[7+i].y},   vlo, B0);
                B1 = pk_fma((v2f){w[7+i].z,   w[7+i].w},   vhi, B1);
                C0 = pk_fma((v2f){w[14+i].x,  w[14+i].y},  vlo, C0);
                C1 = pk_fma((v2f){w[14+i].z,  w[14+i].w},  vhi, C1);
            }
            const v2f As = A0 + A1, Bs = B0 + B1, Cs = C0 + C1;
            float s0 = As.x + As.y;
            float s1 = Bs.x + Bs.y;
            float s2 = Cs.x + Cs.y;
            // ---- quad butterfly (DPP): all 4 lanes get full sums ----
            s0 += quad_xor1(s0); s1 += quad_xor1(s1); s2 += quad_xor1(s2);
            s0 += quad_xor2(s0); s1 += quad_xor2(s1); s2 += quad_xor2(s2);
            // ---- gates + state update, fully in-register ----
            const float rg = fast_sigmoid(gr + s0 + bh0);
            const float zg = fast_sigmoid(gz + s1 + bh1);
            const float na = fmaf(rg, s2 + bh2, gn);
            const float ng = fmaf(2.f, fast_sigmoid(2.f * na), -1.f); // tanh
            const float hv = fmaf(zg, hreg - ng, ng);              // (1-z)*n + z*h
            hreg = hv;
            sum += hv; mx = fmaxf(mx, hv);
            if (p == 0 && q < HDIM) Vh[nxt][q] = hv;               // publish h(t+1)
        } else {
            // ---- producers: prefetch x(t+2), compute gi(t+1) into gib[nxt] ----
            float xv = 0.f;
            const bool doX = (q0 < XDIM) && (t + 2 < T_STEPS);
            if (doX) xv = xsrc[(size_t)(t + 2) * (BATCH * FIN) + xoff];
            if ((t + 1 < T_STEPS) && q0 < 150) {
                const float4* X4 = (const float4*)xbuf[nxt];
                v2f A0 = {0,0}, A1 = {0,0}, B0 = {0,0}, B1 = {0,0};
                #pragma unroll
                for (int i = 0; i < 10; ++i) {
                    const float4 vv = X4[i];
                    const v2f vlo = {vv.x, vv.y}, vhi = {vv.z, vv.w};
                    A0 = pk_fma((v2f){w[i].x,    w[i].y},    vlo, A0);
                    A1 = pk_fma((v2f){w[i].z,    w[i].w},    vhi, A1);
                    B0 = pk_fma((v2f){w[10+i].x, w[10+i].y}, vlo, B0);
                    B1 = pk_fma((v2f){w[10+i].z, w[10+i].w}, vhi, B1);
                }
                const v2f As = A0 + A1, Bs = B0 + B1;
                v2f gv; gv.x = bh0 + (As.x + As.y); gv.y = bh1 + (Bs.x + Bs.y);
                *(v2f*)&gib[nxt][gA] = gv;           // ds_write_b64, linear
            }
            if (doX) xbuf[cur][q0] = xv;
        }
        __syncthreads();
    }

    // ---- pooling + output linear ----
    if (isCons && p == 0 && q < HDIM) {
        feat[q]        = sum / len0[b];
        feat[HDIM + q] = mx;
    }
    __syncthreads();

    if (tid < NCLS) {
        float acc = b_out[tid];
        #pragma unroll 4
        for (int k = 0; k < 2 * HDIM; ++k)
            acc = fmaf(W_out[tid * 2 * HDIM + k], feat[k], acc);
        out[b * NCLS + tid] = acc;
    }
}

extern "C" void kernel_launch(void* const* d_in, const int* in_sizes, int n_in,
                              void* d_out, int out_size, void* d_ws, size_t ws_size,
                              hipStream_t stream)
{
    const float* mfcc0 = (const float*)d_in[0];
    const float* mfcc1 = (const float*)d_in[1];
    const float* mfcc2 = (const float*)d_in[2];
    const float* len0  = (const float*)d_in[3];
    const float* W_ih  = (const float*)d_in[4];
    const float* W_hh  = (const float*)d_in[5];
    const float* b_ih  = (const float*)d_in[6];
    const float* b_hh  = (const float*)d_in[7];
    const float* W_out = (const float*)d_in[8];
    const float* b_out = (const float*)d_in[9];
    float* out = (float*)d_out;

    gru_persistent<<<BATCH, NTHR, 0, stream>>>(
        mfcc0, mfcc1, mfcc2, len0, W_ih, W_hh, b_ih, b_hh, W_out, b_out, out);
}